// Round 7
// baseline (1801.904 us; speedup 1.0000x reference)
//
#include <hip/hip_runtime.h>
#include <hip/hip_bf16.h>
#include <stdint.h>

#define T_SEQ 128
#define NBATCH 32
#define EMBED 512
#define HID 1024
#define NVOCAB 32000
#define NBLK 256   // recurrence worker blocks (block 0 also hosts the sequencer wave)

typedef float f32x4 __attribute__((ext_vector_type(4)));
typedef _Float16 f16x8 __attribute__((ext_vector_type(8)));

__device__ __forceinline__ unsigned short f2h(float f) {
  _Float16 h = (_Float16)f;
  return __builtin_bit_cast(unsigned short, h);
}
__device__ __forceinline__ float sigm(float x) {
  return 1.0f / (1.0f + __expf(-x));
}
__device__ __forceinline__ float tanh_fast(float x) {
  return 2.0f / (1.0f + __expf(-2.0f * x)) - 1.0f;
}

// ---------------- zero the sync flags ----------------
__global__ void k_zero(unsigned int* __restrict__ p, int n) {
  int i = blockIdx.x * blockDim.x + threadIdx.x;
  if (i < n) p[i] = 0;
}

// ---------------- f32 -> f16 convert (vectorized, grid-stride) ----------------
__global__ void k_f32_to_f16(const float4* __restrict__ in,
                             ushort4* __restrict__ out, int n4) {
  int i = blockIdx.x * blockDim.x + threadIdx.x;
  int stride = gridDim.x * blockDim.x;
  for (; i < n4; i += stride) {
    float4 v = in[i];
    ushort4 o;
    o.x = f2h(v.x); o.y = f2h(v.y); o.z = f2h(v.z); o.w = f2h(v.w);
    out[i] = o;
  }
}

// ------------- embedding gather -> A0 f16 [4096][512], row m = t*32+b -------------
__global__ void k_embed(const int* __restrict__ tok, const float* __restrict__ table,
                        ushort4* __restrict__ A0) {
  int tid = blockIdx.x * 256 + threadIdx.x;   // 4096*128 threads total
  int m = tid >> 7, kq = tid & 127;
  int b = m & 31, t = m >> 5;
  int tk = tok[b * T_SEQ + t];
  float4 v = *(const float4*)(table + (size_t)tk * EMBED + kq * 4);
  ushort4 o;
  o.x = f2h(v.x); o.y = f2h(v.y); o.z = f2h(v.z); o.w = f2h(v.w);
  A0[tid] = o;
}

// ---------------- f16 MFMA GEMM: C[M,N] = A[M,K] * B[N,K]^T (+bias) ----------------
// 128x128 tile, BK=64, 4 waves, reg-staged LDS (round-4-exact, proven).
// permute=1: output row m=(t*32+b) is written to row (b*128+t)  [for logits layout]
#define BM 128
#define BN 128
#define BKK 64

__global__ __launch_bounds__(256) void k_gemm_bt(
    const short* __restrict__ A,   // [M,K] f16 bits
    const short* __restrict__ B,   // [N,K] f16 bits
    float* __restrict__ C,
    const float* __restrict__ bias, // [N]
    int M, int N, int K, int permute)
{
  __shared__ __align__(16) short As[BM * BKK];
  __shared__ __align__(16) short Bs[BN * BKK];
  const int tid = threadIdx.x;
  const int w = tid >> 6, l = tid & 63;
  const int wr = w >> 1, wc = w & 1;
  const int bm = blockIdx.x * BM, bn = blockIdx.y * BN;
  const int l15 = l & 15, lkg = l >> 4;

  f32x4 acc[4][4] = {};

  for (int kt = 0; kt < K; kt += BKK) {
#pragma unroll
    for (int p = 0; p < 4; ++p) {
      int idx = p * 2048 + tid * 8;          // element index in [128*64)
      int r = idx >> 6, c = idx & 63;
      *(f16x8*)&As[idx] = *(const f16x8*)&A[(size_t)(bm + r) * K + kt + c];
      *(f16x8*)&Bs[idx] = *(const f16x8*)&B[(size_t)(bn + r) * K + kt + c];
    }
    __syncthreads();

#pragma unroll
    for (int ks = 0; ks < 2; ++ks) {
      f16x8 af[4], bfr[4];
#pragma unroll
      for (int mi = 0; mi < 4; ++mi)
        af[mi] = *(const f16x8*)&As[(wr * 64 + mi * 16 + l15) * BKK + ks * 32 + lkg * 8];
#pragma unroll
      for (int ni = 0; ni < 4; ++ni)
        bfr[ni] = *(const f16x8*)&Bs[(wc * 64 + ni * 16 + l15) * BKK + ks * 32 + lkg * 8];
#pragma unroll
      for (int mi = 0; mi < 4; ++mi)
#pragma unroll
        for (int ni = 0; ni < 4; ++ni)
          acc[mi][ni] = __builtin_amdgcn_mfma_f32_16x16x32_f16(
              af[mi], bfr[ni], acc[mi][ni], 0, 0, 0);
    }
    __syncthreads();
  }

  const int lr = lkg * 4;
#pragma unroll
  for (int mi = 0; mi < 4; ++mi) {
#pragma unroll
    for (int ni = 0; ni < 4; ++ni) {
      int col = bn + wc * 64 + ni * 16 + l15;
      float bv = bias ? bias[col] : 0.0f;
#pragma unroll
      for (int j = 0; j < 4; ++j) {
        int row = bm + wr * 64 + mi * 16 + lr + j;
        int orow = permute ? ((row & 31) * T_SEQ + (row >> 5)) : row;
        C[(size_t)orow * N + col] = acc[mi][ni][j] + bv;
      }
    }
  }
}

// ---------------- fused 2-layer GRU recurrence (persistent, epoch-synced) ----------------
// 256 blocks x 384 threads (grid MUST stay <= 256: cooperative launch with 257
// blocks fails validation silently -> kernel no-op; rounds 5/6 post-mortem).
// Workers: block owns j in [4*bid, 4*bid+4); wave w: role=w>>1
// (0: W_hh0 @ s, 1: W_ih1 @ s-1, 2: W_hh1 @ s-2), nt=w&1 (batch half).
// Sequencer is EMBEDDED in block 0: its wave 0 directly polls the 512 per-wave
// flags (only 1 block polls flags -> no L3 request storm) and republishes two
// monotonic epoch counters (8 replicas, 256B apart). Blocks 1..255 poll ONE
// wave-uniform epoch word each. Publish path per-wave: sc1 h-store,
// s_waitcnt vmcnt(0), lane0 sc1 flag store. One __syncthreads per iter orders
// the bufIH (role1 -> role2) LDS handoff and gates block 0 on its wave-0 poll.
__global__ __launch_bounds__(384, 2) void k_gru_fused(
    const float* __restrict__ gi0,    // [128][32][3072] (includes b_ih0)
    const float* __restrict__ Whh0,   // [3072][1024]
    const float* __restrict__ bhh0,   // [3072]
    const float* __restrict__ Wih1,   // [3072][1024]
    const float* __restrict__ bih1,   // [3072]
    const float* __restrict__ Whh1,   // [3072][1024]
    const float* __restrict__ bhh1,   // [3072]
    const _Float16* __restrict__ h0i, // [32][1024]
    const _Float16* __restrict__ h1i, // [32][1024]
    _Float16* __restrict__ ys0f,      // [128][32][1024]
    _Float16* __restrict__ ys1f,      // [128][32][1024]
    unsigned int* flg0,               // [512]  per-wave: [bid*2+nt]
    unsigned int* flg1,               // [512]
    unsigned int* epoch0,             // [8*64] 8 replicas, stride 64 dwords
    unsigned int* epoch1)             // [8*64]
{
  __shared__ float bufIH[2][3][2][64];  // [parity][gate][nt][lane]

  const int tid = threadIdx.x;
  const int l = tid & 63;
  const int w = tid >> 6;
  const int bid = blockIdx.x;
  const int role = w >> 1, nt = w & 1;
  const int j0 = bid * 4;

  // A-fragment (operand) decode
  const int row16 = l & 15;
  const int jjr = row16 >> 2, gate = row16 & 3;
  const int koct = l >> 4;

  // output (C/D) decode
  const int b_out = nt * 16 + (l & 15);
  const int j_out = j0 + (l >> 4);
  const int jj_even = (((l >> 4) & 1) == 0);

  // ---- load W slice into registers as f16 A-fragments ----
  const float* Wsrc = (role == 0) ? Whh0 : ((role == 1) ? Wih1 : Whh1);
  f16x8 af[32];
  if (gate < 3) {
    const float* wrow = Wsrc + (size_t)(gate * HID + j0 + jjr) * HID;
#pragma unroll
    for (int c = 0; c < 32; ++c) {
      float4 p0 = *(const float4*)(wrow + c * 32 + koct * 8);
      float4 p1 = *(const float4*)(wrow + c * 32 + koct * 8 + 4);
      f16x8 v = { (_Float16)p0.x, (_Float16)p0.y, (_Float16)p0.z, (_Float16)p0.w,
                  (_Float16)p1.x, (_Float16)p1.y, (_Float16)p1.z, (_Float16)p1.w };
      af[c] = v;
    }
  } else {
#pragma unroll
    for (int c = 0; c < 32; ++c) {
      f16x8 z = { (_Float16)0.f, (_Float16)0.f, (_Float16)0.f, (_Float16)0.f,
                  (_Float16)0.f, (_Float16)0.f, (_Float16)0.f, (_Float16)0.f };
      af[c] = z;
    }
  }

  // ---- per-lane bias preloads ----
  float bR = 0.f, bZ = 0.f, bN = 0.f, biR = 0.f, biZ = 0.f, biN = 0.f;
  if (role == 0) {
    bR = bhh0[j_out]; bZ = bhh0[HID + j_out]; bN = bhh0[2 * HID + j_out];
  } else if (role == 2) {
    bR = bhh1[j_out]; bZ = bhh1[HID + j_out]; bN = bhh1[2 * HID + j_out];
    biR = bih1[j_out]; biZ = bih1[HID + j_out]; biN = bih1[2 * HID + j_out];
  }

  // per-lane byte offset into a [32][1024] f16 slab for B-fragment loads
  const int bfragOff = b_out * 2048 + koct * 16;

  // this block's epoch replica (spread blocks over 8 copies)
  const unsigned* ep0 = epoch0 + (bid & 7) * 64;
  const unsigned* ep1 = epoch1 + (bid & 7) * 64;

  for (int s = 0; s <= T_SEQ + 1; ++s) {
    // ---- prefetch flag-independent gi0 values (role 0) ----
    float pre_ir = 0.f, pre_iz = 0.f, pre_in = 0.f;
    if (role == 0 && s < T_SEQ) {
      const float* gib = gi0 + (size_t)(s * NBATCH + b_out) * 3072 + j_out;
      pre_ir = gib[0]; pre_iz = gib[HID]; pre_in = gib[2 * HID];
    }

    if (bid == 0) {
      // ---- block 0, wave 0: direct flag poll for the whole block + epoch publish ----
      if (w == 0) {
        unsigned need0 = (s >= 1 && s <= T_SEQ) ? (unsigned)s : 0u;   // ys0f[s-1]
        unsigned need1 = (s >= 3) ? (unsigned)(s - 2) : 0u;           // ys1f[s-3]
        if ((need0 | need1) != 0u) {
          const unsigned* f0 = flg0 + l * 8;
          const unsigned* f1 = flg1 + l * 8;
          for (;;) {
            unsigned m0 = 0xffffffffu, m1 = 0xffffffffu;
            if (need0) {
#pragma unroll
              for (int i = 0; i < 8; ++i) {
                unsigned v = __hip_atomic_load(f0 + i, __ATOMIC_RELAXED, __HIP_MEMORY_SCOPE_AGENT);
                m0 = v < m0 ? v : m0;
              }
            }
            if (need1) {
#pragma unroll
              for (int i = 0; i < 8; ++i) {
                unsigned v = __hip_atomic_load(f1 + i, __ATOMIC_RELAXED, __HIP_MEMORY_SCOPE_AGENT);
                m1 = v < m1 ? v : m1;
              }
            }
            if (__all(m0 >= need0 && m1 >= need1)) break;
            __builtin_amdgcn_s_sleep(1);
          }
          // republish as epochs (8 replicas each) for blocks 1..255
          if (l < 8) {
            if (need0)
              __hip_atomic_store(epoch0 + l * 64, need0, __ATOMIC_RELAXED, __HIP_MEMORY_SCOPE_AGENT);
            if (need1)
              __hip_atomic_store(epoch1 + l * 64, need1, __ATOMIC_RELAXED, __HIP_MEMORY_SCOPE_AGENT);
          }
          asm volatile("" ::: "memory");
        }
      }
    } else {
      // ---- blocks 1..255: per-wave wait on the single epoch word this role needs ----
      unsigned need = 0;
      const unsigned* ep = ep0;
      if (role == 0) { if (s >= 1 && s < T_SEQ)  need = (unsigned)s; }
      else if (role == 1) { if (s >= 1 && s <= T_SEQ) need = (unsigned)s; }
      else { if (s >= 3) { need = (unsigned)(s - 2); ep = ep1; } }
      if (need) {
        for (;;) {
          unsigned e = __hip_atomic_load(ep, __ATOMIC_RELAXED, __HIP_MEMORY_SCOPE_AGENT);
          if (e >= need) break;
          __builtin_amdgcn_s_sleep(1);
        }
        asm volatile("" ::: "memory");
      }
    }
    __syncthreads();   // gates the block on its wait; publishes bufIH from iter s-1

    // ---------- role 0: layer-0 step t = s ----------
    if (role == 0 && s < T_SEQ) {
      const _Float16* hsrc = (s == 0) ? h0i : (ys0f + (size_t)(s - 1) * NBATCH * HID);
      const char* hb = (const char*)hsrc + bfragOff;
      f32x4 acc0 = {}, acc1 = {};
#pragma unroll
      for (int c = 0; c < 32; c += 2) {
        f16x8 bf0 = *(const f16x8*)(hb + c * 64);
        f16x8 bf1 = *(const f16x8*)(hb + c * 64 + 64);
        acc0 = __builtin_amdgcn_mfma_f32_16x16x32_f16(af[c], bf0, acc0, 0, 0, 0);
        acc1 = __builtin_amdgcn_mfma_f32_16x16x32_f16(af[c + 1], bf1, acc1, 0, 0, 0);
      }
      f32x4 acc = acc0 + acc1;

      float hp = (float)((s == 0) ? h0i[b_out * HID + j_out]
                                  : ys0f[(size_t)((s - 1) * NBATCH + b_out) * HID + j_out]);
      float r = sigm(pre_ir + acc[0] + bR);
      float z = sigm(pre_iz + acc[1] + bZ);
      float n = tanh_fast(pre_in + r * (acc[2] + bN));
      float hnew = (1.0f - z) * n + z * hp;

      unsigned bits = (unsigned)f2h(hnew);
      unsigned hi = __shfl_down(bits, 16);
      if (jj_even) {
        unsigned packed = (bits & 0xffffu) | (hi << 16);
        __hip_atomic_store((unsigned*)(ys0f + (size_t)(s * NBATCH + b_out) * HID + j_out),
                           packed, __ATOMIC_RELAXED, __HIP_MEMORY_SCOPE_AGENT);
      }
      // per-wave publish: h at coherence point, then flag
      asm volatile("s_waitcnt vmcnt(0)" ::: "memory");
      if (l == 0)
        __hip_atomic_store(&flg0[bid * 2 + nt], (unsigned)(s + 1),
                           __ATOMIC_RELAXED, __HIP_MEMORY_SCOPE_AGENT);
    }

    // ---------- role 1: layer-1 input gates for t1 = s-1 -> bufIH[s&1] ----------
    if (role == 1 && s >= 1 && s <= T_SEQ) {
      const _Float16* hsrc = ys0f + (size_t)(s - 1) * NBATCH * HID;
      const char* hb = (const char*)hsrc + bfragOff;
      f32x4 acc0 = {}, acc1 = {};
#pragma unroll
      for (int c = 0; c < 32; c += 2) {
        f16x8 bf0 = *(const f16x8*)(hb + c * 64);
        f16x8 bf1 = *(const f16x8*)(hb + c * 64 + 64);
        acc0 = __builtin_amdgcn_mfma_f32_16x16x32_f16(af[c], bf0, acc0, 0, 0, 0);
        acc1 = __builtin_amdgcn_mfma_f32_16x16x32_f16(af[c + 1], bf1, acc1, 0, 0, 0);
      }
      f32x4 acc = acc0 + acc1;
      bufIH[s & 1][0][nt][l] = acc[0];
      bufIH[s & 1][1][nt][l] = acc[1];
      bufIH[s & 1][2][nt][l] = acc[2];
    }

    // ---------- role 2: layer-1 hidden + combine for t1 = s-2 ----------
    if (role == 2 && s >= 2) {
      const int t1 = s - 2;
      const _Float16* hsrc = (t1 == 0) ? h1i : (ys1f + (size_t)(t1 - 1) * NBATCH * HID);
      const char* hb = (const char*)hsrc + bfragOff;
      f32x4 acc0 = {}, acc1 = {};
#pragma unroll
      for (int c = 0; c < 32; c += 2) {
        f16x8 bf0 = *(const f16x8*)(hb + c * 64);
        f16x8 bf1 = *(const f16x8*)(hb + c * 64 + 64);
        acc0 = __builtin_amdgcn_mfma_f32_16x16x32_f16(af[c], bf0, acc0, 0, 0, 0);
        acc1 = __builtin_amdgcn_mfma_f32_16x16x32_f16(af[c + 1], bf1, acc1, 0, 0, 0);
      }
      f32x4 acc = acc0 + acc1;

      const int par = (s - 1) & 1;
      float ihR = bufIH[par][0][nt][l] + biR;
      float ihZ = bufIH[par][1][nt][l] + biZ;
      float ihN = bufIH[par][2][nt][l] + biN;
      float hp = (float)((t1 == 0) ? h1i[b_out * HID + j_out]
                                   : ys1f[(size_t)((t1 - 1) * NBATCH + b_out) * HID + j_out]);
      float r = sigm(ihR + acc[0] + bR);
      float z = sigm(ihZ + acc[1] + bZ);
      float n = tanh_fast(ihN + r * (acc[2] + bN));
      float hnew = (1.0f - z) * n + z * hp;

      unsigned bits = (unsigned)f2h(hnew);
      unsigned hi = __shfl_down(bits, 16);
      if (jj_even) {
        unsigned packed = (bits & 0xffffu) | (hi << 16);
        __hip_atomic_store((unsigned*)(ys1f + (size_t)(t1 * NBATCH + b_out) * HID + j_out),
                           packed, __ATOMIC_RELAXED, __HIP_MEMORY_SCOPE_AGENT);
      }
      asm volatile("s_waitcnt vmcnt(0)" ::: "memory");
      if (l == 0)
        __hip_atomic_store(&flg1[bid * 2 + nt], (unsigned)(s - 1),
                           __ATOMIC_RELAXED, __HIP_MEMORY_SCOPE_AGENT);
    }
  }
}

// ---------------- host ----------------
extern "C" void kernel_launch(void* const* d_in, const int* in_sizes, int n_in,
                              void* d_out, int out_size, void* d_ws, size_t ws_size,
                              hipStream_t stream)
{
  const int*   inputs = (const int*)d_in[0];
  const float* hidden = (const float*)d_in[2];
  const float* table  = (const float*)d_in[3];
  const float* Wih0   = (const float*)d_in[4];
  const float* Whh0   = (const float*)d_in[5];
  const float* bih0   = (const float*)d_in[6];
  const float* bhh0   = (const float*)d_in[7];
  const float* Wih1   = (const float*)d_in[8];
  const float* Whh1   = (const float*)d_in[9];
  const float* bih1   = (const float*)d_in[10];
  const float* bhh1   = (const float*)d_in[11];
  const float* Wout   = (const float*)d_in[12];
  const float* bout   = (const float*)d_in[13];
  float* out = (float*)d_out;

  char* ws = (char*)d_ws;
  size_t off = 0;
  auto alloc = [&](size_t bytes) {
    void* p = ws + off;
    off += (bytes + 255) & ~(size_t)255;
    return p;
  };
  float*     gi0  = (float*)alloc((size_t)4096 * 3072 * 4);       // 48 MB
  _Float16*  ys0f = (_Float16*)alloc((size_t)4096 * 1024 * 2);    // 8 MB
  _Float16*  ys1f = (_Float16*)alloc((size_t)4096 * 1024 * 2);    // 8 MB
  short*     A0   = (short*)alloc((size_t)4096 * 512 * 2);
  short*     B0   = (short*)alloc((size_t)3072 * 512 * 2);
  short*     B2   = (short*)alloc((size_t)32000 * 1024 * 2);      // 64 MB
  _Float16*  hcat = (_Float16*)alloc((size_t)2 * 32 * 1024 * 2);
  _Float16*  h0i  = hcat;
  _Float16*  h1i  = hcat + 32 * 1024;
  unsigned int* flg0   = (unsigned int*)alloc(512 * 4);
  unsigned int* flg1   = (unsigned int*)alloc(512 * 4);
  unsigned int* epoch0 = (unsigned int*)alloc(512 * 4);
  unsigned int* epoch1 = (unsigned int*)alloc(512 * 4);

  // zero all sync state (flg0..epoch1 are contiguous: 2048 dwords)
  k_zero<<<8, 256, 0, stream>>>(flg0, 2048);

  // conversions
  k_f32_to_f16<<<1024, 256, 0, stream>>>((const float4*)Wih0, (ushort4*)B0, 3072 * 512 / 4);
  k_f32_to_f16<<<2048, 256, 0, stream>>>((const float4*)Wout, (ushort4*)B2, 32000 * 1024 / 4);
  k_f32_to_f16<<<64, 256, 0, stream>>>((const float4*)hidden, (ushort4*)hcat, 2 * 32 * 1024 / 4);
  k_embed<<<2048, 256, 0, stream>>>(inputs, table, (ushort4*)A0);

  // layer-0 input-side gates: gi0 = A0 @ Wih0^T + bih0   [4096,3072]
  dim3 g0(32, 24);
  k_gemm_bt<<<g0, 256, 0, stream>>>(A0, B0, gi0, bih0, 4096, 3072, 512, 0);

  // fused 2-layer recurrence. Grid MUST be <= 256 for cooperative launch
  // (257 fails validation silently -> kernel no-op; rounds 5/6). Fall back to
  // a plain launch if the cooperative launch is rejected (256 blocks at
  // 2 blocks/CU capacity are co-resident either way).
  {
    void* kargs[] = {
      (void*)&gi0, (void*)&Whh0, (void*)&bhh0,
      (void*)&Wih1, (void*)&bih1, (void*)&Whh1, (void*)&bhh1,
      (void*)&h0i, (void*)&h1i, (void*)&ys0f, (void*)&ys1f,
      (void*)&flg0, (void*)&flg1, (void*)&epoch0, (void*)&epoch1
    };
    hipError_t e = hipLaunchCooperativeKernel((const void*)k_gru_fused, dim3(NBLK),
                                              dim3(384), kargs, 0, stream);
    if (e != hipSuccess) {
      (void)hipGetLastError();   // clear error state; fall back to plain launch
      k_gru_fused<<<dim3(NBLK), dim3(384), 0, stream>>>(
          gi0, Whh0, bhh0, Wih1, bih1, Whh1, bhh1,
          h0i, h1i, ys0f, ys1f, flg0, flg1, epoch0, epoch1);
    }
  }

  // output projection: logits[b,s,v]  (row permutation folded into epilogue)
  dim3 g2(32, 250);
  k_gemm_bt<<<g2, 256, 0, stream>>>((const short*)ys1f, B2, out, bout, 4096, 32000, 1024, 1);
}